// Round 17
// baseline (92.792 us; speedup 1.0000x reference)
//
#include <hip/hip_runtime.h>
#include <hip/hip_bf16.h>

// out = exp(Q K^T) V, unnormalized. B=4, S=4096, D=64, fp32 in/out.
// Round 23: 2-tile intra-wave pipeline inside the verified R22 skeleton.
// R22 re-verified the best band (92.1; fill ~44 + prep ~5 + main ~37 +
// reduce ~6). The main loop's ~2.3us/iter floor survived 6 structural
// families; the one shared untested mechanism is the serial pipe-alternating
// chain per tile (MFMA G1 -> VALU exp/trans -> MFMA G2) at only 2 waves/SIMD.
// Fix: process tile PAIRS per barrier iteration (8 iters, 128KB LDS pair
// double-buffer, same vmcnt(0)+1-barrier proof), with interleaved order
//   G1(t0); G1(t1); exp/trans(t0); G2(t0); exp/trans(t1); G2(t1)
// so each stage's latency is covered by the other tile's independent work
// (MFMA and VALU pipes co-schedule; 4 acc chains keep MFMA pipelined).
// Barrier count halves (16->8). Registers ~170 peak (sa0 dead after exp t0),
// no spill at launch_bounds(512,2). prep2/epilogue/reduce_out unchanged.

typedef short    s16x4 __attribute__((ext_vector_type(4)));
typedef short    s16x8 __attribute__((ext_vector_type(8)));
typedef _Float16 h16x8 __attribute__((ext_vector_type(8)));
typedef float    fx4   __attribute__((ext_vector_type(4)));
typedef float    fx16  __attribute__((ext_vector_type(16)));

constexpr int S = 4096, D = 64, BN = 128;
constexpr int QROWS = 128;                          // q-rows per block (main4)
constexpr int TILES = S / BN;                       // 32
constexpr int HALF_TILES = TILES / 2;               // 16 per kk-half
constexpr int PAIRS = HALF_TILES / 2;               // 8 pair-iterations
constexpr int TILE_SHORTS  = 16 * 512;              // 16KB per array per tile
constexpr int BATCH_SHORTS = TILES * TILE_SHORTS;   // 262144

__device__ __forceinline__ unsigned short f2bf(float x) {
    unsigned u = __float_as_uint(x);
    u = (u + 0x7FFFu + ((u >> 16) & 1u)) >> 16;   // RNE
    return (unsigned short)u;
}
__device__ __forceinline__ float bf2f(unsigned short h) {
    return __uint_as_float(((unsigned)h) << 16);
}
__device__ __forceinline__ unsigned short f2h(float x) {
    union { _Float16 h; unsigned short s; } u;
    u.h = (_Float16)x;
    return u.s;
}
__device__ __forceinline__ unsigned pack_bf16(float lo, float hi) {
    __hip_bfloat162 r = __float22bfloat162_rn(make_float2(lo, hi));
    union { __hip_bfloat162 b; unsigned u; } c;
    c.b = r;
    return c.u;
}
__device__ __forceinline__ float ex2(float x) {
#if __has_builtin(__builtin_amdgcn_exp2f)
    return __builtin_amdgcn_exp2f(x);
#else
    return exp2f(x);
#endif
}

// -------- prep: K -> fp16 A-frag order, V -> bf16 B-frag order (32x32x16) ---
// K chunk c = kkq*4+ks : [lane][j] = K[t*128 + kkq*32 + (lane&31)][ks*16 + (lane>>5)*8 + j]
// V chunk c = ss*2+dt  : [lane][j] = V[t*128 + ss*16 + (lane>>5)*8 + j][dt*32 + (lane&31)]
__global__ __launch_bounds__(256) void prep2(
    const float* __restrict__ k, const float* __restrict__ v,
    unsigned short* __restrict__ kf, unsigned short* __restrict__ vf)
{
    __shared__ unsigned short tile[128 * 72];   // row stride 72 halves (pad)
    const int tid   = threadIdx.x;
    const int which = blockIdx.x & 1;           // 0 = K, 1 = V
    const int t     = (blockIdx.x >> 1) & 31;
    const int b     = blockIdx.x >> 6;
    const float* src = (which ? v : k) + ((size_t)b * S + t * BN) * D;

    #pragma unroll
    for (int i = 0; i < 8; ++i) {               // coalesced: 2048 float4s/block
        int f   = i * 256 + tid;
        int row = f >> 4;
        int c4  = (f & 15) << 2;
        float4 x = *(const float4*)(src + row * D + c4);
        s16x4 o;
        if (which) o = (s16x4){(short)f2bf(x.x), (short)f2bf(x.y),
                               (short)f2bf(x.z), (short)f2bf(x.w)};
        else       o = (s16x4){(short)f2h(x.x), (short)f2h(x.y),
                               (short)f2h(x.z), (short)f2h(x.w)};
        *(s16x4*)&tile[row * 72 + c4] = o;
    }
    __syncthreads();

    const int lane = tid & 63;
    unsigned short* dst = (which ? vf : kf) + (size_t)b * BATCH_SHORTS + t * TILE_SHORTS;
    #pragma unroll
    for (int i = 0; i < 4; ++i) {
        int c = (tid >> 6) * 4 + i;             // chunk 0..15
        s16x8 o;
        if (which == 0) {
            int row = (c >> 2) * 32 + (lane & 31);
            int dc  = (c & 3) * 16 + (lane >> 5) * 8;
            o = *(const s16x8*)&tile[row * 72 + dc];     // b128, aligned
        } else {
            int r0 = (c >> 1) * 16 + (lane >> 5) * 8;
            int dc = (c & 1) * 32 + (lane & 31);
            #pragma unroll
            for (int j = 0; j < 8; ++j) o[j] = (short)tile[(r0 + j) * 72 + dc];
        }
        *(s16x8*)(dst + c * 512 + lane * 8) = o;         // coalesced b128
    }
}

// ---------------- main: 128 q-rows per block, one kk-half per block --------
// Tile-PAIR pipeline: 8 barrier iterations, 128KB LDS (2 pair-buffers).
__global__ __launch_bounds__(512, 2) void attn_main4(
    const float* __restrict__ q, const unsigned short* __restrict__ kf,
    const unsigned short* __restrict__ vf, float* __restrict__ partial)
{
    __shared__ unsigned short smem[2 * 4 * TILE_SHORTS];   // 128KB: 2 x pair(K0|V0|K1|V1)

    const int tid = threadIdx.x, lane = tid & 63, w = tid >> 6;
    const int h = lane >> 5, m5 = lane & 31;
    const int mh = w & 1, kkq = w >> 1;         // m-half (64 rows), kk-quarter
    const int b = blockIdx.y, q0 = blockIdx.x * QROWS;
    const int kh = blockIdx.z;                  // kk-half 0/1
    const int t0 = kh * HALF_TILES;

    const unsigned short* kfb = kf + (size_t)b * BATCH_SHORTS;
    const unsigned short* vfb = vf + (size_t)b * BATCH_SHORTS;

    // Q B-frags fp16, pre-scaled by log2(e) so exp(s) = exp2(s').
    // B[k=h*8+j][n=m5] = log2e * Q[q0+mh*64+mt*32+m5][ks*16+h*8+j]
    const float LOG2E = 1.4426950408889634f;
    h16x8 qf[2][4];   // [mt][ks]
    #pragma unroll
    for (int mt = 0; mt < 2; ++mt) {
        const float* qrow = q + ((size_t)b * S + q0 + mh * 64 + mt * 32 + m5) * D + h * 8;
        #pragma unroll
        for (int ks = 0; ks < 4; ++ks) {
            float4 a = *(const float4*)(qrow + ks * 16);
            float4 c = *(const float4*)(qrow + ks * 16 + 4);
            qf[mt][ks] = (h16x8){
                (_Float16)(a.x * LOG2E), (_Float16)(a.y * LOG2E),
                (_Float16)(a.z * LOG2E), (_Float16)(a.w * LOG2E),
                (_Float16)(c.x * LOG2E), (_Float16)(c.y * LOG2E),
                (_Float16)(c.z * LOG2E), (_Float16)(c.w * LOG2E)};
        }
    }

    fx16 oacc[2][2] = {};   // [mt][dt], partial over (kk-quarter, kk-half)

    // Issue one PAIR of tiles (tp, tp+1) into pair-buffer bi: 8 DMAs/wave.
    auto issue = [&](int tp, int bi) {
        unsigned short* base = &smem[bi * 4 * TILE_SHORTS];
        #pragma unroll
        for (int tt = 0; tt < 2; ++tt) {
            #pragma unroll
            for (int ii = 0; ii < 4; ++ii) {             // ii<2: K, else V
                int c = (ii & 1) * 8 + w;                // chunk 0..15
                const unsigned short* g = (ii < 2 ? kfb : vfb)
                    + (size_t)(tp + tt) * TILE_SHORTS + c * 512 + lane * 8;
                unsigned short* l = base + tt * 2 * TILE_SHORTS
                    + (ii < 2 ? 0 : TILE_SHORTS) + c * 512 + lane * 8;
                __builtin_amdgcn_global_load_lds(
                    (const __attribute__((address_space(1))) unsigned int*)g,
                    (__attribute__((address_space(3))) unsigned int*)l, 16, 0, 0);
            }
        }
    };

    union frag { unsigned u[4]; s16x8 v; };

    // GEMM1 for one tile: 8 MFMAs into sa[2].
    auto gemm1 = [&](const unsigned short* kb, fx16* sa) {
        #pragma unroll
        for (int ks = 0; ks < 4; ++ks) {
            h16x8 a = *(const h16x8*)(kb + (kkq * 4 + ks) * 512 + lane * 8);
            #pragma unroll
            for (int mt = 0; mt < 2; ++mt)
                sa[mt] = __builtin_amdgcn_mfma_f32_32x32x16_f16(a, qf[mt][ks], sa[mt], 0, 0, 0);
        }
    };

    // exp2 + bf16 pack + C->A transpose for one tile.
    auto mkA = [&](const fx16* sa, frag A[2][2]) {
        unsigned p01[2][8];
        #pragma unroll
        for (int mt = 0; mt < 2; ++mt)
            #pragma unroll
            for (int rp = 0; rp < 8; ++rp)
                p01[mt][rp] = pack_bf16(ex2(sa[mt][2 * rp]), ex2(sa[mt][2 * rp + 1]));
        #pragma unroll
        for (int mt = 0; mt < 2; ++mt) {
#if __has_builtin(__builtin_amdgcn_permlane32_swap)
            typedef unsigned uix2 __attribute__((ext_vector_type(2)));
            uix2 r0 = __builtin_amdgcn_permlane32_swap(p01[mt][0], p01[mt][2], false, false);
            uix2 r1 = __builtin_amdgcn_permlane32_swap(p01[mt][1], p01[mt][3], false, false);
            A[mt][0].u[0] = r0.x; A[mt][0].u[1] = r1.x;
            A[mt][0].u[2] = r0.y; A[mt][0].u[3] = r1.y;
            uix2 r2 = __builtin_amdgcn_permlane32_swap(p01[mt][4], p01[mt][6], false, false);
            uix2 r3 = __builtin_amdgcn_permlane32_swap(p01[mt][5], p01[mt][7], false, false);
            A[mt][1].u[0] = r2.x; A[mt][1].u[1] = r3.x;
            A[mt][1].u[2] = r2.y; A[mt][1].u[3] = r3.y;
#else
            unsigned sw[8];
            #pragma unroll
            for (int rp = 0; rp < 8; ++rp)
                sw[rp] = (unsigned)__shfl_xor((int)p01[mt][rp], 32, 64);
            A[mt][0].u[0] = h ? sw[2]        : p01[mt][0];
            A[mt][0].u[1] = h ? sw[3]        : p01[mt][1];
            A[mt][0].u[2] = h ? p01[mt][2]   : sw[0];
            A[mt][0].u[3] = h ? p01[mt][3]   : sw[1];
            A[mt][1].u[0] = h ? sw[6]        : p01[mt][4];
            A[mt][1].u[1] = h ? sw[7]        : p01[mt][5];
            A[mt][1].u[2] = h ? p01[mt][6]   : sw[4];
            A[mt][1].u[3] = h ? p01[mt][7]   : sw[5];
#endif
        }
    };

    // GEMM2 for one tile: 8 MFMAs accumulating into oacc.
    auto gemm2 = [&](frag A[2][2], const unsigned short* vb) {
        #pragma unroll
        for (int u = 0; u < 2; ++u) {
            int ss = kkq * 2 + u;                        // 16-kk step in tile
            #pragma unroll
            for (int dt = 0; dt < 2; ++dt) {
                s16x8 vv = *(const s16x8*)(vb + (ss * 2 + dt) * 512 + lane * 8);
                #pragma unroll
                for (int mt = 0; mt < 2; ++mt)
                    oacc[mt][dt] = __builtin_amdgcn_mfma_f32_32x32x16_bf16(
                        A[mt][u].v, vv, oacc[mt][dt], 0, 0, 0);
            }
        }
    };

    issue(t0, 0);

    for (int j = 0; j < PAIRS; ++j) {
        const int bi = j & 1;
        // Wave's 8 DMAs of pair j (issued one iteration ago) landed; the
        // barrier proves all waves finished reading pair-buffer bi^1 last
        // iteration -> safe to refill it.
        __asm__ volatile("" ::: "memory");
        __builtin_amdgcn_s_waitcnt(0x0F70);   // vmcnt(0), lgkm/exp untouched
        __builtin_amdgcn_s_barrier();
        __asm__ volatile("" ::: "memory");
        if (j + 1 < PAIRS) issue(t0 + 2 * (j + 1), bi ^ 1);

        const unsigned short* kb0 = &smem[bi * 4 * TILE_SHORTS];
        const unsigned short* vb0 = kb0 + TILE_SHORTS;
        const unsigned short* kb1 = kb0 + 2 * TILE_SHORTS;
        const unsigned short* vb1 = kb0 + 3 * TILE_SHORTS;

        // Interleaved 2-tile schedule: each stage's latency is covered by
        // the other tile's independent work on the opposite pipe.
        fx16 sa0[2] = {}, sa1[2] = {};
        gemm1(kb0, sa0);          // MFMA (t0)
        gemm1(kb1, sa1);          // MFMA (t1) -- covers sa0 latency
        frag A0[2][2];
        mkA(sa0, A0);             // VALU (t0) -- G1(t1) MFMAs drain behind
        gemm2(A0, vb0);           // MFMA (t0)
        frag A1[2][2];
        mkA(sa1, A1);             // VALU (t1) -- G2(t0) MFMAs drain behind
        gemm2(A1, vb1);           // MFMA (t1)
    }

    // ---- epilogue: reduce 4 kk-quarters per m-half; 2 dt rounds (48KB) ----
    __syncthreads();                     // all DMA drained
    float* scratch = (float*)smem;
    float* pout = partial + ((size_t)kh * gridDim.y + b) * S * D;
    #pragma unroll
    for (int dt = 0; dt < 2; ++dt) {
        if (kkq > 0) {
            float* dst = scratch + (size_t)(mh * 3 + (kkq - 1)) * 2048;
            #pragma unroll
            for (int mt = 0; mt < 2; ++mt)
                #pragma unroll
                for (int r = 0; r < 16; ++r)
                    dst[(mt * 16 + r) * 64 + lane] = oacc[mt][dt][r];
        }
        __syncthreads();
        if (kkq == 0) {
            #pragma unroll
            for (int mt = 0; mt < 2; ++mt)
                #pragma unroll
                for (int r = 0; r < 16; ++r) {
                    float val = oacc[mt][dt][r];
                    #pragma unroll
                    for (int p = 0; p < 3; ++p)
                        val += scratch[(size_t)(mh * 3 + p) * 2048 + (mt * 16 + r) * 64 + lane];
                    int row = q0 + mh * 64 + mt * 32 + (r & 3) + 8 * (r >> 2) + 4 * h;
                    pout[(size_t)row * D + dt * 32 + m5] = val;
                }
        }
        __syncthreads();
    }
}

// ---------------- final reduce: out = partial[0] + partial[1] ----------------
__global__ __launch_bounds__(256) void reduce_out(
    const float4* __restrict__ p0, const float4* __restrict__ p1,
    float4* __restrict__ o, int n4)
{
    int i = blockIdx.x * 256 + threadIdx.x;
    if (i < n4) {
        float4 a = p0[i], b = p1[i];
        o[i] = make_float4(a.x + b.x, a.y + b.y, a.z + b.z, a.w + b.w);
    }
}

// ---------------- fallback (known-good round-2 kernel) ----------------
__global__ __launch_bounds__(1024) void attn_fallback(
    const float* __restrict__ q, const float* __restrict__ k,
    const float* __restrict__ v, float* __restrict__ out)
{
    __shared__ unsigned short Kh[64][72];
    __shared__ unsigned short Kl[64][72];
    __shared__ unsigned short Vt[64][68];
    __shared__ unsigned short Pf[64][72];

    const int tid = threadIdx.x, lane = tid & 63, wave = tid >> 6;
    const int quad = lane >> 4, tq = lane & 15;
    const int kkb = wave & 3, mba = wave >> 2;
    const int b = blockIdx.y, q0 = blockIdx.x * 64;
    const float* qb = q + (size_t)b * S * D;
    const float* kb = k + (size_t)b * S * D;
    const float* vb = v + (size_t)b * S * D;
    float* ob = out + (size_t)b * S * D;

    s16x8 qh[2], ql[2];
    {
        const float* qrow = qb + (size_t)(q0 + mba * 16 + tq) * D;
        #pragma unroll
        for (int ks = 0; ks < 2; ++ks) {
            const float* src = qrow + ks * 32 + quad * 8;
            float4 f0 = *(const float4*)src;
            float4 f1 = *(const float4*)(src + 4);
            float f[8] = {f0.x, f0.y, f0.z, f0.w, f1.x, f1.y, f1.z, f1.w};
            #pragma unroll
            for (int j = 0; j < 8; ++j) {
                unsigned short hh = f2bf(f[j]);
                qh[ks][j] = (short)hh;
                ql[ks][j] = (short)f2bf(f[j] - bf2f(hh));
            }
        }
    }
    fx4 oacc = {0.f, 0.f, 0.f, 0.f};
    const int krow = tid >> 4, kc4 = (tid & 15) << 2;
    const int vd = tid & 63, vk = (tid >> 6) << 2;

    for (int t = 0; t < S / 64; ++t) {
        __syncthreads();
        const float* kt = kb + (size_t)(t * 64 + krow) * D;
        const float* vt = vb + (size_t)(t * 64 + vk) * D;
        {
            float4 kv = *(const float4*)(kt + kc4);
            unsigned short h0 = f2bf(kv.x), h1 = f2bf(kv.y), h2 = f2bf(kv.z), h3 = f2bf(kv.w);
            s16x4 a = {(short)h0, (short)h1, (short)h2, (short)h3};
            s16x4 l4 = {(short)f2bf(kv.x - bf2f(h0)), (short)f2bf(kv.y - bf2f(h1)),
                        (short)f2bf(kv.z - bf2f(h2)), (short)f2bf(kv.w - bf2f(h3))};
            *(s16x4*)&Kh[krow][kc4] = a;
            *(s16x4*)&Kl[krow][kc4] = l4;
            const float* vs = vt + vd;
            s16x4 vv = {(short)f2bf(vs[0]), (short)f2bf(vs[D]),
                        (short)f2bf(vs[2 * D]), (short)f2bf(vs[3 * D])};
            *(s16x4*)&Vt[vd][vk] = vv;
        }
        __syncthreads();
        fx4 sacc = {0.f, 0.f, 0.f, 0.f};
        #pragma unroll
        for (int ks = 0; ks < 2; ++ks) {
            s16x8 kah = *(const s16x8*)&Kh[kkb * 16 + tq][ks * 32 + quad * 8];
            s16x8 kal = *(const s16x8*)&Kl[kkb * 16 + tq][ks * 32 + quad * 8];
            sacc = __builtin_amdgcn_mfma_f32_16x16x32_bf16(kah, qh[ks], sacc, 0, 0, 0);
            sacc = __builtin_amdgcn_mfma_f32_16x16x32_bf16(kah, ql[ks], sacc, 0, 0, 0);
            sacc = __builtin_amdgcn_mfma_f32_16x16x32_bf16(kal, qh[ks], sacc, 0, 0, 0);
        }
        s16x4 pp = {(short)f2bf(__expf(sacc[0])), (short)f2bf(__expf(sacc[1])),
                    (short)f2bf(__expf(sacc[2])), (short)f2bf(__expf(sacc[3]))};
        *(s16x4*)&Pf[mba * 16 + tq][kkb * 16 + (quad << 2)] = pp;
        __syncthreads();
        #pragma unroll
        for (int ks = 0; ks < 2; ++ks) {
            s16x8 pa = *(const s16x8*)&Pf[mba * 16 + tq][ks * 32 + quad * 8];
            const unsigned short* vr = &Vt[kkb * 16 + tq][ks * 32 + quad * 8];
            s16x4 va = *(const s16x4*)vr;
            s16x4 vb2 = *(const s16x4*)(vr + 4);
            s16x8 vfull = __builtin_shufflevector(va, vb2, 0, 1, 2, 3, 4, 5, 6, 7);
            oacc = __builtin_amdgcn_mfma_f32_16x16x32_bf16(pa, vfull, oacc, 0, 0, 0);
        }
    }
    #pragma unroll
    for (int r = 0; r < 4; ++r)
        ob[(size_t)(q0 + mba * 16 + quad * 4 + r) * D + kkb * 16 + tq] = oacc[r];
}

extern "C" void kernel_launch(void* const* d_in, const int* in_sizes, int n_in,
                              void* d_out, int out_size, void* d_ws, size_t ws_size,
                              hipStream_t stream) {
    const float* q = (const float*)d_in[0];
    const float* k = (const float*)d_in[1];
    const float* v = (const float*)d_in[2];
    float* out = (float*)d_out;
    const int nbatch = in_sizes[0] / (S * D);   // 4
    const size_t elems = (size_t)nbatch * S * D;

    // ws: kf (fp16, 2MB) | vf (bf16, 2MB) | partial[2] (fp32, 8MB) = 12MB
    const size_t need = elems * 2 * 2 + elems * 2 * 4;
    if (nbatch == 4 && ws_size >= need && d_ws != nullptr) {
        unsigned short* kf = (unsigned short*)d_ws;
        unsigned short* vf = kf + elems;
        float* partial = (float*)(vf + elems);

        prep2<<<nbatch * TILES * 2, 256, 0, stream>>>(k, v, kf, vf);
        dim3 grid(S / QROWS, nbatch, 2);
        attn_main4<<<grid, 512, 0, stream>>>(q, kf, vf, partial);
        const int n4 = (int)(elems / 4);
        reduce_out<<<(n4 + 255) / 256, 256, 0, stream>>>(
            (const float4*)partial, (const float4*)(partial + elems),
            (float4*)out, n4);
    } else {
        dim3 grid(S / 64, nbatch);
        attn_fallback<<<grid, 1024, 0, stream>>>(q, k, v, out);
    }
}